// Round 1
// baseline (405.248 us; speedup 1.0000x reference)
//
#include <hip/hip_runtime.h>
#include <math.h>

// ---------------------------------------------------------------------------
// YOLO loss, forward only.
// Key insight: only the objectness channel (1/85 of the data) is needed
// densely; box+cls channels are needed only at <=1536 positive cells.
// ---------------------------------------------------------------------------

#define IMGF 640.0f
#define NCLS 80
#define NAK 3
#define NB 16
#define NT 32
#define H0 80
#define H1 40
#define H2 20
#define NCELL0 (NB * NAK * H0 * H0) /* 307200 */
#define NCELL1 (NB * NAK * H1 * H1) /*  76800 */
#define NCELL2 (NB * NAK * H2 * H2) /*  19200 */
#define NCELL_TOTAL (NCELL0 + NCELL1 + NCELL2) /* 403200 */

__device__ __constant__ float c_anchors[9][2] = {
    {0.0156f, 0.0203f}, {0.025f, 0.0469f}, {0.0516f, 0.0359f},
    {0.0469f, 0.0953f}, {0.0969f, 0.0703f}, {0.0922f, 0.1859f},
    {0.1813f, 0.1406f}, {0.2438f, 0.3094f}, {0.5828f, 0.5094f}};

__device__ inline float sgm(float x) { return 1.f / (1.f + expf(-x)); }
__device__ inline float bcef(float x, float t) {
    return fmaxf(x, 0.f) - x * t + log1pf(expf(-fabsf(x)));
}

// One thread per target (b,n). Scatters last-writer order index (atomicMax)
// and class-union bitmask (atomicOr) into per-cell workspace arrays.
__global__ __launch_bounds__(512) void assign_kernel(
    const float* __restrict__ boxes, const int* __restrict__ labels,
    int* __restrict__ order, unsigned int* __restrict__ clsmask) {
    int t = threadIdx.x;
    if (t >= NB * NT) return;
    int b = t >> 5;
    float x1 = boxes[4 * t + 0], y1 = boxes[4 * t + 1];
    float x2 = boxes[4 * t + 2], y2 = boxes[4 * t + 3];
    float bw = fminf(fmaxf((x2 - x1) / IMGF, 1e-6f), 1.0f);
    float bh = fminf(fmaxf((y2 - y1) / IMGF, 1e-6f), 1.0f);
    int lab = labels[t];
    if (lab < 0 || lab >= NCLS) return; // invalid -> contributes nothing
    float area = bw * bh;
    float best = -1.0f;
    int bestk = 0;
#pragma unroll
    for (int k = 0; k < 9; k++) { // first max wins (strict >) == jnp.argmax
        float aw = c_anchors[k][0], ah = c_anchors[k][1];
        float inter = fminf(bw, aw) * fminf(bh, ah);
        float iou = inter / (area + aw * ah - inter + 1e-9f);
        if (iou > best) { best = iou; bestk = k; }
    }
    int s = bestk / 3, a = bestk - 3 * s;
    float cx = fminf(fmaxf((x1 + x2) * 0.5f / IMGF, 0.f), 1.f - 1e-6f);
    float cy = fminf(fmaxf((y1 + y2) * 0.5f / IMGF, 0.f), 1.f - 1e-6f);
    int hw = (s == 0) ? H0 : ((s == 1) ? H1 : H2);
    int basecell = (s == 0) ? 0 : ((s == 1) ? NCELL0 : (NCELL0 + NCELL1));
    float gx = cx * (float)hw, gy = cy * (float)hw;
    int gi = (int)floorf(gx); gi = min(max(gi, 0), hw - 1);
    int gj = (int)floorf(gy); gj = min(max(gj, 0), hw - 1);
    float fx = gx - (float)gi, fy = gy - (float)gj;
    const int dis[5] = {0, -1, 1, 0, 0};
    const int djs[5] = {0, 0, 0, -1, 1};
    bool keep[5];
    keep[0] = true;
    keep[1] = (fx < 0.5f);
    keep[2] = (fx >= 0.5f);
    keep[3] = (fy < 0.5f);
    keep[4] = (fy >= 0.5f);
    unsigned int mbit = 1u << (lab & 31);
    int mword = lab >> 5;
#pragma unroll
    for (int c = 0; c < 5; c++) {
        if (!keep[c]) continue;
        int ngi = gi + dis[c], ngj = gj + djs[c];
        if (ngi < 0 || ngi >= hw || ngj < 0 || ngj >= hw) continue;
        int cell = basecell + ((b * NAK + a) * hw + ngj) * hw + ngi;
        // scan-order index of this scatter update (c outermost, then b, n):
        // replicates XLA-CPU scatter-set "last write wins" for box_t.
        atomicMax(&order[cell], c * (NB * NT) + t);
        atomicOr(&clsmask[(size_t)cell * 3 + mword], mbit);
    }
}

// One thread per cell across all three scales.
__global__ __launch_bounds__(256) void dense_kernel(
    const float* __restrict__ p0, const float* __restrict__ p1,
    const float* __restrict__ p2, const float* __restrict__ boxes,
    const int* __restrict__ order, const unsigned int* __restrict__ clsmask,
    float* __restrict__ accum) {
    int idx = blockIdx.x * blockDim.x + threadIdx.x;
    float obj_c = 0.f, cls_c = 0.f, box_c = 0.f, npos_c = 0.f;
    if (idx < NCELL_TOTAL) {
        const float* p;
        int hw, s, base;
        float inv;
        if (idx < NCELL0) {
            p = p0; hw = H0; s = 0; base = 0; inv = 1.f / (float)NCELL0;
        } else if (idx < NCELL0 + NCELL1) {
            p = p1; hw = H1; s = 1; base = NCELL0; inv = 1.f / (float)NCELL1;
        } else {
            p = p2; hw = H2; s = 2; base = NCELL0 + NCELL1; inv = 1.f / (float)NCELL2;
        }
        int cell = idx - base;
        int x = cell % hw;
        int r = cell / hw;
        int y = r % hw;
        r /= hw;
        int a = r % NAK;
        int b = r / NAK;
        size_t HW = (size_t)hw * hw;
        const float* pc = p + (size_t)(b * 255 + a * 85) * HW + (size_t)y * hw + x;
        float pobj = pc[4 * HW];
        int o = order[idx];
        float t = (o >= 0) ? 1.f : 0.f;
        // focal(x,t) * bce(x,t); obj/noobj weights are both 1.0
        float pp = sgm(pobj);
        float pt = pp * t + (1.f - pp) * (1.f - t);
        float at = 0.25f * t + 0.75f * (1.f - t);
        float omp = 1.f - pt;
        obj_c = at * omp * omp * bcef(pobj, t) * inv; // per-scale mean folded in
        npos_c = t;
        if (o >= 0) {
            // ---- class loss (union one-hot target from bitmask) ----
            unsigned m0 = clsmask[(size_t)idx * 3 + 0];
            unsigned m1 = clsmask[(size_t)idx * 3 + 1];
            unsigned m2 = clsmask[(size_t)idx * 3 + 2];
            float cl = 0.f;
            for (int c = 0; c < NCLS; c++) {
                unsigned w = (c < 32) ? m0 : ((c < 64) ? m1 : m2);
                float tt = ((w >> (c & 31)) & 1u) ? 1.f : 0.f;
                cl += bcef(pc[(size_t)(5 + c) * HW], tt);
            }
            cls_c = cl;
            // ---- box loss: decode winning target from order index ----
            int wn = o % (NB * NT);
            float bx1 = boxes[4 * wn + 0], by1 = boxes[4 * wn + 1];
            float bx2 = boxes[4 * wn + 2], by2 = boxes[4 * wn + 3];
            float tw = fminf(fmaxf((bx2 - bx1) / IMGF, 1e-6f), 1.f);
            float th = fminf(fmaxf((by2 - by1) / IMGF, 1e-6f), 1.f);
            float tcx = fminf(fmaxf((bx1 + bx2) * 0.5f / IMGF, 0.f), 1.f - 1e-6f);
            float tcy = fminf(fmaxf((by1 + by2) * 0.5f / IMGF, 0.f), 1.f - 1e-6f);
            float l0 = pc[0], l1 = pc[HW], l2 = pc[2 * HW], l3 = pc[3 * HW];
            float pcx = ((float)x + 2.f * sgm(l0) - 0.5f) / (float)hw;
            float pcy = ((float)y + 2.f * sgm(l1) - 0.5f) / (float)hw;
            float sw = 2.f * sgm(l2), sh = 2.f * sgm(l3);
            float pw = sw * sw * c_anchors[s * 3 + a][0];
            float ph = sh * sh * c_anchors[s * 3 + a][1];
            float px1 = pcx - pw * 0.5f, px2 = pcx + pw * 0.5f;
            float py1 = pcy - ph * 0.5f, py2 = pcy + ph * 0.5f;
            float tx1 = tcx - tw * 0.5f, tx2 = tcx + tw * 0.5f;
            float ty1 = tcy - th * 0.5f, ty2 = tcy + th * 0.5f;
            float iw = fmaxf(fminf(px2, tx2) - fmaxf(px1, tx1), 0.f);
            float ih = fmaxf(fminf(py2, ty2) - fmaxf(py1, ty1), 0.f);
            float it = iw * ih;
            float un = pw * ph + tw * th - it + 1e-9f;
            float iou = it / un;
            float enc = (fmaxf(px2, tx2) - fminf(px1, tx1)) *
                        (fmaxf(py2, ty2) - fminf(py1, ty1)) + 1e-9f;
            float giou = iou - (enc - un) / enc;
            float l1l = fabsf(pcx - tcx) + fabsf(pcy - tcy) +
                        fabsf(pw - tw) + fabsf(ph - th);
            box_c = 1.f - giou + l1l;
        }
    }
    // wave-64 tree reduce, one atomicAdd per wave per quantity
#pragma unroll
    for (int off = 32; off > 0; off >>= 1) {
        obj_c += __shfl_down(obj_c, off, 64);
        cls_c += __shfl_down(cls_c, off, 64);
        box_c += __shfl_down(box_c, off, 64);
        npos_c += __shfl_down(npos_c, off, 64);
    }
    if ((threadIdx.x & 63) == 0) {
        atomicAdd(&accum[0], obj_c);
        atomicAdd(&accum[1], cls_c);
        atomicAdd(&accum[2], box_c);
        atomicAdd(&accum[3], npos_c);
    }
}

__global__ void finalize_kernel(const float* __restrict__ accum,
                                float* __restrict__ out) {
    if (threadIdx.x == 0 && blockIdx.x == 0) {
        float d = fmaxf(accum[3], 1.f);
        out[0] = accum[0] + (accum[1] + 5.f * accum[2]) / d;
    }
}

extern "C" void kernel_launch(void* const* d_in, const int* in_sizes, int n_in,
                              void* d_out, int out_size, void* d_ws,
                              size_t ws_size, hipStream_t stream) {
    const float* p0 = (const float*)d_in[0];
    const float* p1 = (const float*)d_in[1];
    const float* p2 = (const float*)d_in[2];
    const float* boxes = (const float*)d_in[3];
    const int* labels = (const int*)d_in[4];
    float* out = (float*)d_out;

    // workspace layout: [order int32 x NCELL_TOTAL][clsmask u32 x NCELL_TOTAL*3][accum f32 x 4]
    char* ws = (char*)d_ws;
    int* order = (int*)ws;
    size_t order_bytes = (size_t)NCELL_TOTAL * 4;
    unsigned int* clsmask = (unsigned int*)(ws + order_bytes);
    size_t mask_bytes = (size_t)NCELL_TOTAL * 12;
    float* accum = (float*)(ws + order_bytes + mask_bytes);

    hipMemsetAsync(order, 0xFF, order_bytes, stream);            // order = -1
    hipMemsetAsync(clsmask, 0, mask_bytes + 4 * sizeof(float), stream); // masks+accum = 0

    assign_kernel<<<1, 512, 0, stream>>>(boxes, labels, order, clsmask);
    dense_kernel<<<(NCELL_TOTAL + 255) / 256, 256, 0, stream>>>(
        p0, p1, p2, boxes, order, clsmask, accum);
    finalize_kernel<<<1, 64, 0, stream>>>(accum, out);
}

// Round 2
// 110.785 us; speedup vs baseline: 3.6580x; 3.6580x over previous
//
#include <hip/hip_runtime.h>
#include <math.h>

// ---------------------------------------------------------------------------
// YOLO loss, forward only.
// Structure: assign (512 thr, scatter per-cell metadata) -> dense (one thread
// per cell, block-reduced partials, NO global atomics) -> finalize (1 block).
// Only the objectness channel (1/85 of the 137 MB input) is read densely;
// box+cls channels are read only at the <=1536 positive cells.
// ---------------------------------------------------------------------------

#define IMGF 640.0f
#define NCLS 80
#define NAK 3
#define NB 16
#define NT 32
#define H0 80
#define H1 40
#define H2 20
#define NCELL0 (NB * NAK * H0 * H0) /* 307200 */
#define NCELL1 (NB * NAK * H1 * H1) /*  76800 */
#define NCELL2 (NB * NAK * H2 * H2) /*  19200 */
#define NCELL_TOTAL (NCELL0 + NCELL1 + NCELL2) /* 403200 */
#define DENSE_BLOCK 256
#define NBLK ((NCELL_TOTAL + DENSE_BLOCK - 1) / DENSE_BLOCK) /* 1575 */

__device__ __constant__ float c_anchors[9][2] = {
    {0.0156f, 0.0203f}, {0.025f, 0.0469f}, {0.0516f, 0.0359f},
    {0.0469f, 0.0953f}, {0.0969f, 0.0703f}, {0.0922f, 0.1859f},
    {0.1813f, 0.1406f}, {0.2438f, 0.3094f}, {0.5828f, 0.5094f}};

__device__ inline float sgm(float x) { return 1.f / (1.f + expf(-x)); }
__device__ inline float bcef(float x, float t) {
    return fmaxf(x, 0.f) - x * t + log1pf(expf(-fabsf(x)));
}

// One thread per target (b,n). Scatters:
//  - order[cell]: atomicMax of scan-order index (c*512+t) -> last-writer-wins
//    box target (replicates XLA scatter-set order), doubles as pos flag.
//  - tmask[cell]: atomicOr of (1<<n) -> which targets of this batch hit the
//    cell (labels re-read later to build the class-union one-hot).
__global__ __launch_bounds__(512) void assign_kernel(
    const float* __restrict__ boxes, const int* __restrict__ labels,
    int* __restrict__ order, unsigned int* __restrict__ tmask) {
    int t = threadIdx.x;
    if (t >= NB * NT) return;
    int b = t >> 5;
    int n = t & 31;
    float x1 = boxes[4 * t + 0], y1 = boxes[4 * t + 1];
    float x2 = boxes[4 * t + 2], y2 = boxes[4 * t + 3];
    float bw = fminf(fmaxf((x2 - x1) / IMGF, 1e-6f), 1.0f);
    float bh = fminf(fmaxf((y2 - y1) / IMGF, 1e-6f), 1.0f);
    int lab = labels[t];
    if (lab < 0 || lab >= NCLS) return; // invalid -> contributes nothing
    float area = bw * bh;
    float best = -1.0f;
    int bestk = 0;
#pragma unroll
    for (int k = 0; k < 9; k++) { // first max wins (strict >) == jnp.argmax
        float aw = c_anchors[k][0], ah = c_anchors[k][1];
        float inter = fminf(bw, aw) * fminf(bh, ah);
        float iou = inter / (area + aw * ah - inter + 1e-9f);
        if (iou > best) { best = iou; bestk = k; }
    }
    int s = bestk / 3, a = bestk - 3 * s;
    float cx = fminf(fmaxf((x1 + x2) * 0.5f / IMGF, 0.f), 1.f - 1e-6f);
    float cy = fminf(fmaxf((y1 + y2) * 0.5f / IMGF, 0.f), 1.f - 1e-6f);
    int hw = (s == 0) ? H0 : ((s == 1) ? H1 : H2);
    int basecell = (s == 0) ? 0 : ((s == 1) ? NCELL0 : (NCELL0 + NCELL1));
    float gx = cx * (float)hw, gy = cy * (float)hw;
    int gi = (int)floorf(gx); gi = min(max(gi, 0), hw - 1);
    int gj = (int)floorf(gy); gj = min(max(gj, 0), hw - 1);
    float fx = gx - (float)gi, fy = gy - (float)gj;
    const int dis[5] = {0, -1, 1, 0, 0};
    const int djs[5] = {0, 0, 0, -1, 1};
    bool keep[5];
    keep[0] = true;
    keep[1] = (fx < 0.5f);
    keep[2] = (fx >= 0.5f);
    keep[3] = (fy < 0.5f);
    keep[4] = (fy >= 0.5f);
#pragma unroll
    for (int c = 0; c < 5; c++) {
        if (!keep[c]) continue;
        int ngi = gi + dis[c], ngj = gj + djs[c];
        if (ngi < 0 || ngi >= hw || ngj < 0 || ngj >= hw) continue;
        int cell = basecell + ((b * NAK + a) * hw + ngj) * hw + ngi;
        atomicMax(&order[cell], c * (NB * NT) + t);
        atomicOr(&tmask[cell], 1u << n);
    }
}

// One thread per cell across all three scales. Block-reduces in LDS and
// writes 4 partials per block to disjoint slots — no global atomics.
__global__ __launch_bounds__(DENSE_BLOCK) void dense_kernel(
    const float* __restrict__ p0, const float* __restrict__ p1,
    const float* __restrict__ p2, const float* __restrict__ boxes,
    const int* __restrict__ labels, const int* __restrict__ order,
    const unsigned int* __restrict__ tmask, float* __restrict__ partials) {
    int idx = blockIdx.x * blockDim.x + threadIdx.x;
    float obj_c = 0.f, cls_c = 0.f, box_c = 0.f, npos_c = 0.f;
    if (idx < NCELL_TOTAL) {
        const float* p;
        int hw, s, base;
        float inv;
        if (idx < NCELL0) {
            p = p0; hw = H0; s = 0; base = 0; inv = 1.f / (float)NCELL0;
        } else if (idx < NCELL0 + NCELL1) {
            p = p1; hw = H1; s = 1; base = NCELL0; inv = 1.f / (float)NCELL1;
        } else {
            p = p2; hw = H2; s = 2; base = NCELL0 + NCELL1; inv = 1.f / (float)NCELL2;
        }
        int cell = idx - base;
        int x = cell % hw;
        int r = cell / hw;
        int y = r % hw;
        r /= hw;
        int a = r % NAK;
        int b = r / NAK;
        size_t HW = (size_t)hw * hw;
        const float* pc = p + (size_t)(b * 255 + a * 85) * HW + (size_t)y * hw + x;
        float pobj = pc[4 * HW];
        unsigned tm = tmask[idx];
        float t = (tm != 0u) ? 1.f : 0.f;
        // focal(x,t) * bce(x,t); obj/noobj weights are both 1.0
        float pp = sgm(pobj);
        float pt = pp * t + (1.f - pp) * (1.f - t);
        float at = 0.25f * t + 0.75f * (1.f - t);
        float omp = 1.f - pt;
        obj_c = at * omp * omp * bcef(pobj, t) * inv; // per-scale mean folded in
        npos_c = t;
        if (tm != 0u) {
            // ---- class-union one-hot from contributing targets ----
            unsigned m0 = 0, m1 = 0, m2 = 0, tmp = tm;
            while (tmp) {
                int n = __ffs(tmp) - 1;
                tmp &= tmp - 1;
                int lab = labels[(b << 5) + n];
                if (lab < 32) m0 |= 1u << lab;
                else if (lab < 64) m1 |= 1u << (lab - 32);
                else m2 |= 1u << (lab - 64);
            }
            float cl = 0.f;
            for (int c = 0; c < NCLS; c++) {
                unsigned w = (c < 32) ? m0 : ((c < 64) ? m1 : m2);
                float tt = ((w >> (c & 31)) & 1u) ? 1.f : 0.f;
                cl += bcef(pc[(size_t)(5 + c) * HW], tt);
            }
            cls_c = cl;
            // ---- box loss: decode winning target from order index ----
            int o = order[idx];
            int wn = o % (NB * NT);
            float bx1 = boxes[4 * wn + 0], by1 = boxes[4 * wn + 1];
            float bx2 = boxes[4 * wn + 2], by2 = boxes[4 * wn + 3];
            float tw = fminf(fmaxf((bx2 - bx1) / IMGF, 1e-6f), 1.f);
            float th = fminf(fmaxf((by2 - by1) / IMGF, 1e-6f), 1.f);
            float tcx = fminf(fmaxf((bx1 + bx2) * 0.5f / IMGF, 0.f), 1.f - 1e-6f);
            float tcy = fminf(fmaxf((by1 + by2) * 0.5f / IMGF, 0.f), 1.f - 1e-6f);
            float l0 = pc[0], l1 = pc[HW], l2 = pc[2 * HW], l3 = pc[3 * HW];
            float pcx = ((float)x + 2.f * sgm(l0) - 0.5f) / (float)hw;
            float pcy = ((float)y + 2.f * sgm(l1) - 0.5f) / (float)hw;
            float sw = 2.f * sgm(l2), sh = 2.f * sgm(l3);
            float pw = sw * sw * c_anchors[s * 3 + a][0];
            float ph = sh * sh * c_anchors[s * 3 + a][1];
            float px1 = pcx - pw * 0.5f, px2 = pcx + pw * 0.5f;
            float py1 = pcy - ph * 0.5f, py2 = pcy + ph * 0.5f;
            float tx1 = tcx - tw * 0.5f, tx2 = tcx + tw * 0.5f;
            float ty1 = tcy - th * 0.5f, ty2 = tcy + th * 0.5f;
            float iw = fmaxf(fminf(px2, tx2) - fmaxf(px1, tx1), 0.f);
            float ih = fmaxf(fminf(py2, ty2) - fmaxf(py1, ty1), 0.f);
            float it = iw * ih;
            float un = pw * ph + tw * th - it + 1e-9f;
            float iou = it / un;
            float enc = (fmaxf(px2, tx2) - fminf(px1, tx1)) *
                        (fmaxf(py2, ty2) - fminf(py1, ty1)) + 1e-9f;
            float giou = iou - (enc - un) / enc;
            float l1l = fabsf(pcx - tcx) + fabsf(pcy - tcy) +
                        fabsf(pw - tw) + fabsf(ph - th);
            box_c = 1.f - giou + l1l;
        }
    }
    // wave-64 tree reduce
#pragma unroll
    for (int off = 32; off > 0; off >>= 1) {
        obj_c += __shfl_down(obj_c, off, 64);
        cls_c += __shfl_down(cls_c, off, 64);
        box_c += __shfl_down(box_c, off, 64);
        npos_c += __shfl_down(npos_c, off, 64);
    }
    __shared__ float red[4][4]; // [wave][quantity]
    int wv = threadIdx.x >> 6;
    if ((threadIdx.x & 63) == 0) {
        red[wv][0] = obj_c;
        red[wv][1] = cls_c;
        red[wv][2] = box_c;
        red[wv][3] = npos_c;
    }
    __syncthreads();
    if (threadIdx.x == 0) {
        float* dst = partials + (size_t)blockIdx.x * 4;
        dst[0] = red[0][0] + red[1][0] + red[2][0] + red[3][0];
        dst[1] = red[0][1] + red[1][1] + red[2][1] + red[3][1];
        dst[2] = red[0][2] + red[1][2] + red[2][2] + red[3][2];
        dst[3] = red[0][3] + red[1][3] + red[2][3] + red[3][3];
    }
}

// One block: reduce NBLK partial quadruples, write scalar loss.
__global__ __launch_bounds__(256) void finalize_kernel(
    const float* __restrict__ partials, float* __restrict__ out) {
    float s0 = 0.f, s1 = 0.f, s2 = 0.f, s3 = 0.f;
    for (int i = threadIdx.x; i < NBLK; i += 256) {
        const float* src = partials + (size_t)i * 4;
        s0 += src[0];
        s1 += src[1];
        s2 += src[2];
        s3 += src[3];
    }
#pragma unroll
    for (int off = 32; off > 0; off >>= 1) {
        s0 += __shfl_down(s0, off, 64);
        s1 += __shfl_down(s1, off, 64);
        s2 += __shfl_down(s2, off, 64);
        s3 += __shfl_down(s3, off, 64);
    }
    __shared__ float red[4][4];
    int wv = threadIdx.x >> 6;
    if ((threadIdx.x & 63) == 0) {
        red[wv][0] = s0;
        red[wv][1] = s1;
        red[wv][2] = s2;
        red[wv][3] = s3;
    }
    __syncthreads();
    if (threadIdx.x == 0) {
        float obj = red[0][0] + red[1][0] + red[2][0] + red[3][0];
        float cls = red[0][1] + red[1][1] + red[2][1] + red[3][1];
        float box = red[0][2] + red[1][2] + red[2][2] + red[3][2];
        float npos = red[0][3] + red[1][3] + red[2][3] + red[3][3];
        float d = fmaxf(npos, 1.f);
        out[0] = obj + (cls + 5.f * box) / d;
    }
}

extern "C" void kernel_launch(void* const* d_in, const int* in_sizes, int n_in,
                              void* d_out, int out_size, void* d_ws,
                              size_t ws_size, hipStream_t stream) {
    const float* p0 = (const float*)d_in[0];
    const float* p1 = (const float*)d_in[1];
    const float* p2 = (const float*)d_in[2];
    const float* boxes = (const float*)d_in[3];
    const int* labels = (const int*)d_in[4];
    float* out = (float*)d_out;

    // ws layout: [order i32 x NCELL][tmask u32 x NCELL][partials f32 x NBLK*4]
    char* ws = (char*)d_ws;
    int* order = (int*)ws;
    size_t order_bytes = (size_t)NCELL_TOTAL * 4;
    unsigned int* tmask = (unsigned int*)(ws + order_bytes);
    size_t tmask_bytes = (size_t)NCELL_TOTAL * 4;
    float* partials = (float*)(ws + order_bytes + tmask_bytes);

    hipMemsetAsync(order, 0xFF, order_bytes, stream); // order = -1
    hipMemsetAsync(tmask, 0, tmask_bytes, stream);    // tmask = 0

    assign_kernel<<<1, 512, 0, stream>>>(boxes, labels, order, tmask);
    dense_kernel<<<NBLK, DENSE_BLOCK, 0, stream>>>(p0, p1, p2, boxes, labels,
                                                   order, tmask, partials);
    finalize_kernel<<<1, 256, 0, stream>>>(partials, out);
}

// Round 3
// 34.704 us; speedup vs baseline: 11.6773x; 3.1923x over previous
//
#include <hip/hip_runtime.h>
#include <math.h>

// ---------------------------------------------------------------------------
// YOLO loss, forward only.
//   assign   : 512 threads, scatter per-cell {order, tmask} + compact list of
//              positive cells (append on first claim). list length == npos.
//   dense    : obj loss only, 4 cells/thread (float4/uint4), block partials.
//   pos      : ONE WAVE per positive cell — 80 class logits loaded by 80
//              lanes in parallel (kills the 80-deep serial load chain that
//              dominated round 2), box loss on lane 0.
//   finalize : reduce partials, combine.
// ---------------------------------------------------------------------------

#define IMGF 640.0f
#define NCLS 80
#define NAK 3
#define NB 16
#define NT 32
#define H0 80
#define H1 40
#define H2 20
#define NCELL0 (NB * NAK * H0 * H0) /* 307200 */
#define NCELL1 (NB * NAK * H1 * H1) /*  76800 */
#define NCELL2 (NB * NAK * H2 * H2) /*  19200 */
#define NCELL_TOTAL (NCELL0 + NCELL1 + NCELL2) /* 403200 */
#define MAXPOS (5 * NB * NT) /* 2560 */
#define NDENSE (NCELL_TOTAL / 4) /* 100800 */
#define NDBLK ((NDENSE + 255) / 256) /* 394 */

__device__ __constant__ float c_anchors[9][2] = {
    {0.0156f, 0.0203f}, {0.025f, 0.0469f}, {0.0516f, 0.0359f},
    {0.0469f, 0.0953f}, {0.0969f, 0.0703f}, {0.0922f, 0.1859f},
    {0.1813f, 0.1406f}, {0.2438f, 0.3094f}, {0.5828f, 0.5094f}};

__device__ inline float sgm(float x) { return 1.f / (1.f + expf(-x)); }
__device__ inline float bcef(float x, float t) {
    return fmaxf(x, 0.f) - x * t + log1pf(expf(-fabsf(x)));
}
__device__ inline float focal_bce(float x, float t) {
    float p = sgm(x);
    float pt = p * t + (1.f - p) * (1.f - t);
    float at = 0.25f * t + 0.75f * (1.f - t);
    float omp = 1.f - pt;
    return at * omp * omp * bcef(x, t);
}

// ---------------- assign ----------------
__global__ __launch_bounds__(512) void assign_kernel(
    const float* __restrict__ boxes, const int* __restrict__ labels,
    int* __restrict__ order, unsigned int* __restrict__ tmask,
    int* __restrict__ count, int* __restrict__ list) {
    int t = threadIdx.x;
    if (t >= NB * NT) return;
    int b = t >> 5;
    int n = t & 31;
    int lab = labels[t];
    if (lab < 0 || lab >= NCLS) return;
    float x1 = boxes[4 * t + 0], y1 = boxes[4 * t + 1];
    float x2 = boxes[4 * t + 2], y2 = boxes[4 * t + 3];
    float bw = fminf(fmaxf((x2 - x1) / IMGF, 1e-6f), 1.0f);
    float bh = fminf(fmaxf((y2 - y1) / IMGF, 1e-6f), 1.0f);
    float area = bw * bh;
    float best = -1.0f;
    int bestk = 0;
#pragma unroll
    for (int k = 0; k < 9; k++) { // strict > == jnp.argmax first-max
        float aw = c_anchors[k][0], ah = c_anchors[k][1];
        float inter = fminf(bw, aw) * fminf(bh, ah);
        float iou = inter / (area + aw * ah - inter + 1e-9f);
        if (iou > best) { best = iou; bestk = k; }
    }
    int s = bestk / 3, a = bestk - 3 * s;
    float cx = fminf(fmaxf((x1 + x2) * 0.5f / IMGF, 0.f), 1.f - 1e-6f);
    float cy = fminf(fmaxf((y1 + y2) * 0.5f / IMGF, 0.f), 1.f - 1e-6f);
    int hw = (s == 0) ? H0 : ((s == 1) ? H1 : H2);
    int basecell = (s == 0) ? 0 : ((s == 1) ? NCELL0 : (NCELL0 + NCELL1));
    float gx = cx * (float)hw, gy = cy * (float)hw;
    int gi = min(max((int)floorf(gx), 0), hw - 1);
    int gj = min(max((int)floorf(gy), 0), hw - 1);
    float fx = gx - (float)gi, fy = gy - (float)gj;
    const int dis[5] = {0, -1, 1, 0, 0};
    const int djs[5] = {0, 0, 0, -1, 1};
    bool keep[5];
    keep[0] = true;
    keep[1] = (fx < 0.5f);
    keep[2] = (fx >= 0.5f);
    keep[3] = (fy < 0.5f);
    keep[4] = (fy >= 0.5f);
#pragma unroll
    for (int c = 0; c < 5; c++) {
        if (!keep[c]) continue;
        int ngi = gi + dis[c], ngj = gj + djs[c];
        if (ngi < 0 || ngi >= hw || ngj < 0 || ngj >= hw) continue;
        int cell = basecell + ((b * NAK + a) * hw + ngj) * hw + ngi;
        // scan-order index: last-writer-wins box target (XLA scatter-set)
        int old = atomicMax(&order[cell], c * (NB * NT) + t);
        atomicOr(&tmask[cell], 1u << n);
        if (old == -1) { // first claim -> append to compact positive list
            int pos = atomicAdd(count, 1);
            list[pos] = cell;
        }
    }
}

// ---------------- dense obj ----------------
template <int HWC>
__device__ inline float obj4(const float* __restrict__ p, uint4 tm, int cis,
                             float inv) {
    int q = cis / HWC; // (b*3+a); compile-time divisor -> magic mul
    int off = cis - q * HWC;
    const float4 v =
        *reinterpret_cast<const float4*>(p + ((size_t)q * 85 + 4) * HWC + off);
    float o = focal_bce(v.x, tm.x ? 1.f : 0.f);
    o += focal_bce(v.y, tm.y ? 1.f : 0.f);
    o += focal_bce(v.z, tm.z ? 1.f : 0.f);
    o += focal_bce(v.w, tm.w ? 1.f : 0.f);
    return o * inv;
}

__global__ __launch_bounds__(256) void dense_kernel(
    const float* __restrict__ p0, const float* __restrict__ p1,
    const float* __restrict__ p2, const uint4* __restrict__ tmask4,
    float* __restrict__ dpart) {
    int i = blockIdx.x * 256 + threadIdx.x;
    float obj = 0.f;
    if (i < NDENSE) {
        uint4 tm = tmask4[i];
        int c4 = i * 4;
        if (c4 < NCELL0)
            obj = obj4<H0 * H0>(p0, tm, c4, 1.f / (float)NCELL0);
        else if (c4 < NCELL0 + NCELL1)
            obj = obj4<H1 * H1>(p1, tm, c4 - NCELL0, 1.f / (float)NCELL1);
        else
            obj = obj4<H2 * H2>(p2, tm, c4 - NCELL0 - NCELL1,
                                1.f / (float)NCELL2);
    }
#pragma unroll
    for (int off = 32; off > 0; off >>= 1) obj += __shfl_down(obj, off, 64);
    __shared__ float red[4];
    if ((threadIdx.x & 63) == 0) red[threadIdx.x >> 6] = obj;
    __syncthreads();
    if (threadIdx.x == 0)
        dpart[blockIdx.x] = red[0] + red[1] + red[2] + red[3];
}

// ---------------- positive cells: one wave per cell ----------------
__global__ __launch_bounds__(256) void pos_kernel(
    const float* __restrict__ p0, const float* __restrict__ p1,
    const float* __restrict__ p2, const float* __restrict__ boxes,
    const int* __restrict__ labels, const int* __restrict__ order,
    const unsigned int* __restrict__ tmask, const int* __restrict__ count,
    const int* __restrict__ list, float* __restrict__ ppart) {
    int w = (blockIdx.x * 256 + threadIdx.x) >> 6;
    int lane = threadIdx.x & 63;
    if (w >= *count) return; // wave-uniform
    int idx = list[w];
    const float* p;
    int hw, s, base;
    if (idx < NCELL0) {
        p = p0; hw = H0; s = 0; base = 0;
    } else if (idx < NCELL0 + NCELL1) {
        p = p1; hw = H1; s = 1; base = NCELL0;
    } else {
        p = p2; hw = H2; s = 2; base = NCELL0 + NCELL1;
    }
    int cell = idx - base;
    int x = cell % hw;
    int r = cell / hw;
    int y = r % hw;
    r /= hw;
    int a = r % NAK;
    int b = r / NAK;
    size_t HW = (size_t)hw * hw;
    const float* pc = p + (size_t)(b * 255 + a * 85) * HW + (size_t)y * hw + x;
    unsigned tm = tmask[idx];
    // class loss: classes spread across lanes (2 rounds of parallel loads)
    float cl = 0.f;
#pragma unroll
    for (int rep = 0; rep < 2; rep++) {
        int c = lane + 64 * rep;
        if (c < NCLS) {
            float tt = 0.f;
            unsigned tmp = tm;
            while (tmp) {
                int n = __ffs(tmp) - 1;
                tmp &= tmp - 1;
                if (labels[(b << 5) + n] == c) tt = 1.f;
            }
            cl += bcef(pc[(size_t)(5 + c) * HW], tt);
        }
    }
#pragma unroll
    for (int off = 32; off > 0; off >>= 1) cl += __shfl_down(cl, off, 64);
    if (lane == 0) {
        // box loss: decode winning target (last scatter writer)
        int wn = order[idx] & (NB * NT - 1); // o % 512
        float bx1 = boxes[4 * wn + 0], by1 = boxes[4 * wn + 1];
        float bx2 = boxes[4 * wn + 2], by2 = boxes[4 * wn + 3];
        float tw = fminf(fmaxf((bx2 - bx1) / IMGF, 1e-6f), 1.f);
        float th = fminf(fmaxf((by2 - by1) / IMGF, 1e-6f), 1.f);
        float tcx = fminf(fmaxf((bx1 + bx2) * 0.5f / IMGF, 0.f), 1.f - 1e-6f);
        float tcy = fminf(fmaxf((by1 + by2) * 0.5f / IMGF, 0.f), 1.f - 1e-6f);
        float l0 = pc[0], l1 = pc[HW], l2 = pc[2 * HW], l3 = pc[3 * HW];
        float pcx = ((float)x + 2.f * sgm(l0) - 0.5f) / (float)hw;
        float pcy = ((float)y + 2.f * sgm(l1) - 0.5f) / (float)hw;
        float sw = 2.f * sgm(l2), sh = 2.f * sgm(l3);
        float pw = sw * sw * c_anchors[s * 3 + a][0];
        float ph = sh * sh * c_anchors[s * 3 + a][1];
        float px1 = pcx - pw * 0.5f, px2 = pcx + pw * 0.5f;
        float py1 = pcy - ph * 0.5f, py2 = pcy + ph * 0.5f;
        float tx1 = tcx - tw * 0.5f, tx2 = tcx + tw * 0.5f;
        float ty1 = tcy - th * 0.5f, ty2 = tcy + th * 0.5f;
        float iw = fmaxf(fminf(px2, tx2) - fmaxf(px1, tx1), 0.f);
        float ih = fmaxf(fminf(py2, ty2) - fmaxf(py1, ty1), 0.f);
        float it = iw * ih;
        float un = pw * ph + tw * th - it + 1e-9f;
        float iou = it / un;
        float enc = (fmaxf(px2, tx2) - fminf(px1, tx1)) *
                        (fmaxf(py2, ty2) - fminf(py1, ty1)) +
                    1e-9f;
        float giou = iou - (enc - un) / enc;
        float l1l = fabsf(pcx - tcx) + fabsf(pcy - tcy) + fabsf(pw - tw) +
                    fabsf(ph - th);
        ppart[2 * w] = cl;
        ppart[2 * w + 1] = 1.f - giou + l1l;
    }
}

// ---------------- finalize ----------------
__global__ __launch_bounds__(256) void finalize_kernel(
    const float* __restrict__ dpart, const float* __restrict__ ppart,
    const int* __restrict__ count, float* __restrict__ out) {
    int cnt = *count;
    float obj = 0.f, cls = 0.f, box = 0.f;
    for (int i = threadIdx.x; i < NDBLK; i += 256) obj += dpart[i];
    for (int i = threadIdx.x; i < cnt; i += 256) {
        cls += ppart[2 * i];
        box += ppart[2 * i + 1];
    }
#pragma unroll
    for (int off = 32; off > 0; off >>= 1) {
        obj += __shfl_down(obj, off, 64);
        cls += __shfl_down(cls, off, 64);
        box += __shfl_down(box, off, 64);
    }
    __shared__ float red[4][3];
    int wv = threadIdx.x >> 6;
    if ((threadIdx.x & 63) == 0) {
        red[wv][0] = obj;
        red[wv][1] = cls;
        red[wv][2] = box;
    }
    __syncthreads();
    if (threadIdx.x == 0) {
        float o = red[0][0] + red[1][0] + red[2][0] + red[3][0];
        float c = red[0][1] + red[1][1] + red[2][1] + red[3][1];
        float bx = red[0][2] + red[1][2] + red[2][2] + red[3][2];
        float d = fmaxf((float)cnt, 1.f);
        out[0] = o + (c + 5.f * bx) / d;
    }
}

extern "C" void kernel_launch(void* const* d_in, const int* in_sizes, int n_in,
                              void* d_out, int out_size, void* d_ws,
                              size_t ws_size, hipStream_t stream) {
    const float* p0 = (const float*)d_in[0];
    const float* p1 = (const float*)d_in[1];
    const float* p2 = (const float*)d_in[2];
    const float* boxes = (const float*)d_in[3];
    const int* labels = (const int*)d_in[4];
    float* out = (float*)d_out;

    // ws layout (16B-aligned regions):
    // [order i32 x NCELL][tmask u32 x NCELL][count i32 (+pad 16B)]
    // [list i32 x MAXPOS][dpart f32 x NDBLK(pad)][ppart f32 x MAXPOS*2]
    char* ws = (char*)d_ws;
    int* order = (int*)ws;
    size_t off = (size_t)NCELL_TOTAL * 4;
    unsigned int* tmask = (unsigned int*)(ws + off);
    off += (size_t)NCELL_TOTAL * 4;
    int* count = (int*)(ws + off);
    off += 16;
    int* list = (int*)(ws + off);
    off += (size_t)MAXPOS * 4;
    float* dpart = (float*)(ws + off);
    off += (size_t)((NDBLK + 3) / 4 * 4) * 4;
    float* ppart = (float*)(ws + off);

    hipMemsetAsync(order, 0xFF, (size_t)NCELL_TOTAL * 4, stream); // order=-1
    hipMemsetAsync(tmask, 0, (size_t)NCELL_TOTAL * 4 + 16, stream); // +count

    assign_kernel<<<1, 512, 0, stream>>>(boxes, labels, order, tmask, count,
                                         list);
    dense_kernel<<<NDBLK, 256, 0, stream>>>(p0, p1, p2, (const uint4*)tmask,
                                            dpart);
    pos_kernel<<<(MAXPOS * 64 + 255) / 256, 256, 0, stream>>>(
        p0, p1, p2, boxes, labels, order, tmask, count, list, ppart);
    finalize_kernel<<<1, 256, 0, stream>>>(dpart, ppart, count, out);
}

// Round 4
// 31.187 us; speedup vs baseline: 12.9941x; 1.1128x over previous
//
#include <hip/hip_runtime.h>
#include <math.h>

// ---------------------------------------------------------------------------
// YOLO loss, forward only. 3 dispatches, 0 memsets:
//   assign : 1 block / 512 threads (one per target). Candidates are deduped
//            in an LDS hash table (CAS claim + atomicMax order + atomicOr
//            target mask), compacted to a global list + count. Also resets
//            the done-counter for the pos kernel's fused finalize.
//   dense  : obj loss with t=0 for ALL cells — pure coalesced float4 stream
//            of the obj channel (1.6 MB), no per-cell state, block partials.
//   pos    : one wave per positive cell. Corrects obj (t=0 -> t=1), class
//            loss with 80 classes spread over lanes, box GIoU+L1 on lane 0.
//            Last finishing block reduces all partials and writes the loss.
// ---------------------------------------------------------------------------

#define IMGF 640.0f
#define NCLS 80
#define NAK 3
#define NB 16
#define NT 32
#define H0 80
#define H1 40
#define H2 20
#define NCELL0 (NB * NAK * H0 * H0) /* 307200 */
#define NCELL1 (NB * NAK * H1 * H1) /*  76800 */
#define NCELL2 (NB * NAK * H2 * H2) /*  19200 */
#define NCELL_TOTAL (NCELL0 + NCELL1 + NCELL2) /* 403200 */
#define MAXPOS 1536 /* <=3 candidates per target x 512 targets */
#define NDENSE (NCELL_TOTAL / 4) /* 100800 */
#define NDBLK ((NDENSE + 255) / 256) /* 394 */
#define POS_BLOCKS (MAXPOS * 64 / 256) /* 384 */
#define HSIZE 4096

__device__ __constant__ float c_anchors[9][2] = {
    {0.0156f, 0.0203f}, {0.025f, 0.0469f}, {0.0516f, 0.0359f},
    {0.0469f, 0.0953f}, {0.0969f, 0.0703f}, {0.0922f, 0.1859f},
    {0.1813f, 0.1406f}, {0.2438f, 0.3094f}, {0.5828f, 0.5094f}};

__device__ inline float sgm(float x) { return 1.f / (1.f + expf(-x)); }
__device__ inline float bcef(float x, float t) {
    return fmaxf(x, 0.f) - x * t + log1pf(expf(-fabsf(x)));
}
__device__ inline float focal_bce(float x, float t) {
    float p = sgm(x);
    float pt = p * t + (1.f - p) * (1.f - t);
    float at = 0.25f * t + 0.75f * (1.f - t);
    float omp = 1.f - pt;
    return at * omp * omp * bcef(x, t);
}

// ---------------- assign: LDS-hash dedup -> compact list ----------------
__global__ __launch_bounds__(512) void assign_kernel(
    const float* __restrict__ boxes, const int* __restrict__ labels,
    int4* __restrict__ list, int* __restrict__ countg, int* __restrict__ done) {
    __shared__ int hkey[HSIZE];
    __shared__ int hord[HSIZE];
    __shared__ unsigned htm[HSIZE];
    __shared__ int lcount;
    for (int i = threadIdx.x; i < HSIZE; i += 512) {
        hkey[i] = -1;
        hord[i] = -1;
        htm[i] = 0u;
    }
    if (threadIdx.x == 0) lcount = 0;
    __syncthreads();

    int t = threadIdx.x;
    int b = t >> 5;
    int n = t & 31;
    int lab = labels[t];
    if (lab >= 0 && lab < NCLS) {
        float x1 = boxes[4 * t + 0], y1 = boxes[4 * t + 1];
        float x2 = boxes[4 * t + 2], y2 = boxes[4 * t + 3];
        float bw = fminf(fmaxf((x2 - x1) / IMGF, 1e-6f), 1.0f);
        float bh = fminf(fmaxf((y2 - y1) / IMGF, 1e-6f), 1.0f);
        float area = bw * bh;
        float best = -1.0f;
        int bestk = 0;
#pragma unroll
        for (int k = 0; k < 9; k++) { // strict > == jnp.argmax first-max
            float aw = c_anchors[k][0], ah = c_anchors[k][1];
            float inter = fminf(bw, aw) * fminf(bh, ah);
            float iou = inter / (area + aw * ah - inter + 1e-9f);
            if (iou > best) { best = iou; bestk = k; }
        }
        int s = bestk / 3, a = bestk - 3 * s;
        float cx = fminf(fmaxf((x1 + x2) * 0.5f / IMGF, 0.f), 1.f - 1e-6f);
        float cy = fminf(fmaxf((y1 + y2) * 0.5f / IMGF, 0.f), 1.f - 1e-6f);
        int hw = (s == 0) ? H0 : ((s == 1) ? H1 : H2);
        int basecell = (s == 0) ? 0 : ((s == 1) ? NCELL0 : (NCELL0 + NCELL1));
        float gx = cx * (float)hw, gy = cy * (float)hw;
        int gi = min(max((int)floorf(gx), 0), hw - 1);
        int gj = min(max((int)floorf(gy), 0), hw - 1);
        float fx = gx - (float)gi, fy = gy - (float)gj;
        const int dis[5] = {0, -1, 1, 0, 0};
        const int djs[5] = {0, 0, 0, -1, 1};
        bool keep[5];
        keep[0] = true;
        keep[1] = (fx < 0.5f);
        keep[2] = (fx >= 0.5f);
        keep[3] = (fy < 0.5f);
        keep[4] = (fy >= 0.5f);
#pragma unroll
        for (int c = 0; c < 5; c++) {
            if (!keep[c]) continue;
            int ngi = gi + dis[c], ngj = gj + djs[c];
            if (ngi < 0 || ngi >= hw || ngj < 0 || ngj >= hw) continue;
            int cell = basecell + ((b * NAK + a) * hw + ngj) * hw + ngi;
            unsigned h = ((unsigned)cell * 2654435761u) >> 20; // 12 bits
            while (true) {
                int old = atomicCAS(&hkey[h], -1, cell);
                if (old == -1 || old == cell) break;
                h = (h + 1) & (HSIZE - 1);
            }
            // scan-order key: last-writer-wins box target (XLA scatter-set)
            atomicMax(&hord[h], c * (NB * NT) + t);
            atomicOr(&htm[h], 1u << n);
        }
    }
    __syncthreads();
    // compact occupied slots to the global list
    for (int i = threadIdx.x; i < HSIZE; i += 512) {
        if (hkey[i] >= 0) {
            int p = atomicAdd(&lcount, 1);
            list[p] = make_int4(hkey[i], hord[i], (int)htm[i], 0);
        }
    }
    __syncthreads();
    if (threadIdx.x == 0) {
        *countg = lcount;
        *done = 0; // reset fused-finalize protocol for pos_kernel
    }
}

// ---------------- dense obj (t = 0 everywhere) ----------------
template <int HWC>
__device__ inline float obj4(const float* __restrict__ p, int cis, float inv) {
    int q = cis / HWC; // (b*3+a); compile-time divisor -> magic mul
    int off = cis - q * HWC;
    const float4 v =
        *reinterpret_cast<const float4*>(p + ((size_t)q * 85 + 4) * HWC + off);
    return (focal_bce(v.x, 0.f) + focal_bce(v.y, 0.f) + focal_bce(v.z, 0.f) +
            focal_bce(v.w, 0.f)) *
           inv;
}

__global__ __launch_bounds__(256) void dense_kernel(
    const float* __restrict__ p0, const float* __restrict__ p1,
    const float* __restrict__ p2, float* __restrict__ dpart) {
    int i = blockIdx.x * 256 + threadIdx.x;
    float obj = 0.f;
    if (i < NDENSE) {
        int c4 = i * 4;
        if (c4 < NCELL0)
            obj = obj4<H0 * H0>(p0, c4, 1.f / (float)NCELL0);
        else if (c4 < NCELL0 + NCELL1)
            obj = obj4<H1 * H1>(p1, c4 - NCELL0, 1.f / (float)NCELL1);
        else
            obj = obj4<H2 * H2>(p2, c4 - NCELL0 - NCELL1, 1.f / (float)NCELL2);
    }
#pragma unroll
    for (int off = 32; off > 0; off >>= 1) obj += __shfl_down(obj, off, 64);
    __shared__ float red[4];
    if ((threadIdx.x & 63) == 0) red[threadIdx.x >> 6] = obj;
    __syncthreads();
    if (threadIdx.x == 0)
        dpart[blockIdx.x] = red[0] + red[1] + red[2] + red[3];
}

// ---------------- positives: one wave/cell + fused finalize ----------------
__global__ __launch_bounds__(256) void pos_kernel(
    const float* __restrict__ p0, const float* __restrict__ p1,
    const float* __restrict__ p2, const float* __restrict__ boxes,
    const int* __restrict__ labels, const int4* __restrict__ list,
    const int* __restrict__ countg, int* __restrict__ done,
    const float* __restrict__ dpart, float* __restrict__ ppart,
    float* __restrict__ out) {
    int cnt = *countg;
    int w = (blockIdx.x * 256 + threadIdx.x) >> 6;
    int lane = threadIdx.x & 63;
    if (w < cnt) {
        int4 rec = list[w];
        int idx = rec.x;
        unsigned tm = (unsigned)rec.z;
        const float* p;
        int hw, s, base;
        float inv;
        if (idx < NCELL0) {
            p = p0; hw = H0; s = 0; base = 0; inv = 1.f / (float)NCELL0;
        } else if (idx < NCELL0 + NCELL1) {
            p = p1; hw = H1; s = 1; base = NCELL0; inv = 1.f / (float)NCELL1;
        } else {
            p = p2; hw = H2; s = 2; base = NCELL0 + NCELL1;
            inv = 1.f / (float)NCELL2;
        }
        int cell = idx - base;
        int x = cell % hw;
        int r = cell / hw;
        int y = r % hw;
        r /= hw;
        int a = r % NAK;
        int b = r / NAK;
        size_t HW = (size_t)hw * hw;
        const float* pc =
            p + (size_t)(b * 255 + a * 85) * HW + (size_t)y * hw + x;
        // class loss: 80 classes over lanes (2 rounds of parallel loads)
        float cl = 0.f;
#pragma unroll
        for (int rep = 0; rep < 2; rep++) {
            int c = lane + 64 * rep;
            if (c < NCLS) {
                float tt = 0.f;
                unsigned tmp = tm;
                while (tmp) {
                    int n = __ffs(tmp) - 1;
                    tmp &= tmp - 1;
                    if (labels[(b << 5) + n] == c) tt = 1.f;
                }
                cl += bcef(pc[(size_t)(5 + c) * HW], tt);
            }
        }
#pragma unroll
        for (int off = 32; off > 0; off >>= 1) cl += __shfl_down(cl, off, 64);
        if (lane == 0) {
            // obj correction t=0 -> t=1 (dense assumed t=0 here)
            float pobj = pc[4 * HW];
            float objc = (focal_bce(pobj, 1.f) - focal_bce(pobj, 0.f)) * inv;
            // box loss: decode last scatter writer
            int wn = rec.y & (NB * NT - 1); // order % 512
            float bx1 = boxes[4 * wn + 0], by1 = boxes[4 * wn + 1];
            float bx2 = boxes[4 * wn + 2], by2 = boxes[4 * wn + 3];
            float tw = fminf(fmaxf((bx2 - bx1) / IMGF, 1e-6f), 1.f);
            float th = fminf(fmaxf((by2 - by1) / IMGF, 1e-6f), 1.f);
            float tcx =
                fminf(fmaxf((bx1 + bx2) * 0.5f / IMGF, 0.f), 1.f - 1e-6f);
            float tcy =
                fminf(fmaxf((by1 + by2) * 0.5f / IMGF, 0.f), 1.f - 1e-6f);
            float l0 = pc[0], l1 = pc[HW], l2 = pc[2 * HW], l3 = pc[3 * HW];
            float pcx = ((float)x + 2.f * sgm(l0) - 0.5f) / (float)hw;
            float pcy = ((float)y + 2.f * sgm(l1) - 0.5f) / (float)hw;
            float sw = 2.f * sgm(l2), sh = 2.f * sgm(l3);
            float pw = sw * sw * c_anchors[s * 3 + a][0];
            float ph = sh * sh * c_anchors[s * 3 + a][1];
            float px1 = pcx - pw * 0.5f, px2 = pcx + pw * 0.5f;
            float py1 = pcy - ph * 0.5f, py2 = pcy + ph * 0.5f;
            float tx1 = tcx - tw * 0.5f, tx2 = tcx + tw * 0.5f;
            float ty1 = tcy - th * 0.5f, ty2 = tcy + th * 0.5f;
            float iw = fmaxf(fminf(px2, tx2) - fmaxf(px1, tx1), 0.f);
            float ih = fmaxf(fminf(py2, ty2) - fmaxf(py1, ty1), 0.f);
            float it = iw * ih;
            float un = pw * ph + tw * th - it + 1e-9f;
            float iou = it / un;
            float enc = (fmaxf(px2, tx2) - fminf(px1, tx1)) *
                            (fmaxf(py2, ty2) - fminf(py1, ty1)) +
                        1e-9f;
            float giou = iou - (enc - un) / enc;
            float l1l = fabsf(pcx - tcx) + fabsf(pcy - tcy) + fabsf(pw - tw) +
                        fabsf(ph - th);
            ppart[3 * w] = cl;
            ppart[3 * w + 1] = 1.f - giou + l1l;
            ppart[3 * w + 2] = objc;
        }
    }
    // ---- fused finalize: last block to finish reduces everything ----
    __shared__ int amLast;
    __syncthreads();
    if (threadIdx.x == 0) {
        __threadfence(); // release our partial writes device-wide
        int old = atomicAdd(done, 1);
        amLast = (old == POS_BLOCKS - 1) ? 1 : 0;
    }
    __syncthreads();
    if (amLast) {
        __threadfence(); // acquire other blocks' writes
        float obj = 0.f, cls = 0.f, box = 0.f;
        for (int i = threadIdx.x; i < NDBLK; i += 256) obj += dpart[i];
        for (int i = threadIdx.x; i < cnt; i += 256) {
            cls += ppart[3 * i];
            box += ppart[3 * i + 1];
            obj += ppart[3 * i + 2];
        }
#pragma unroll
        for (int off = 32; off > 0; off >>= 1) {
            obj += __shfl_down(obj, off, 64);
            cls += __shfl_down(cls, off, 64);
            box += __shfl_down(box, off, 64);
        }
        __shared__ float red[4][3];
        int wv = threadIdx.x >> 6;
        if ((threadIdx.x & 63) == 0) {
            red[wv][0] = obj;
            red[wv][1] = cls;
            red[wv][2] = box;
        }
        __syncthreads();
        if (threadIdx.x == 0) {
            float o = red[0][0] + red[1][0] + red[2][0] + red[3][0];
            float c = red[0][1] + red[1][1] + red[2][1] + red[3][1];
            float bx = red[0][2] + red[1][2] + red[2][2] + red[3][2];
            float d = fmaxf((float)cnt, 1.f);
            out[0] = o + (c + 5.f * bx) / d;
        }
    }
}

extern "C" void kernel_launch(void* const* d_in, const int* in_sizes, int n_in,
                              void* d_out, int out_size, void* d_ws,
                              size_t ws_size, hipStream_t stream) {
    const float* p0 = (const float*)d_in[0];
    const float* p1 = (const float*)d_in[1];
    const float* p2 = (const float*)d_in[2];
    const float* boxes = (const float*)d_in[3];
    const int* labels = (const int*)d_in[4];
    float* out = (float*)d_out;

    // ws layout (all regions written before read every call; no init needed):
    // [list int4 x MAXPOS][count i32][done i32][pad][dpart f32 x NDBLK]
    // [ppart f32 x MAXPOS*3]
    char* ws = (char*)d_ws;
    int4* list = (int4*)ws;
    size_t off = (size_t)MAXPOS * 16; // 24576
    int* countg = (int*)(ws + off);
    int* done = (int*)(ws + off + 4);
    off += 16;
    float* dpart = (float*)(ws + off);
    off += (size_t)((NDBLK + 3) / 4 * 4) * 4;
    float* ppart = (float*)(ws + off);

    assign_kernel<<<1, 512, 0, stream>>>(boxes, labels, list, countg, done);
    dense_kernel<<<NDBLK, 256, 0, stream>>>(p0, p1, p2, dpart);
    pos_kernel<<<POS_BLOCKS, 256, 0, stream>>>(p0, p1, p2, boxes, labels, list,
                                               countg, done, dpart, ppart, out);
}